// Round 2
// baseline (188.953 us; speedup 1.0000x reference)
//
#include <hip/hip_runtime.h>

#define N_TOK 9216
#define C_DIM 64
#define I_DIM 32
#define BOT 16
#define B_SZ 2
#define N_TILES 144  // N_TOK / 64

typedef short bf16x8 __attribute__((ext_vector_type(8)));
typedef float f32x4 __attribute__((ext_vector_type(4)));
typedef float f32x16 __attribute__((ext_vector_type(16)));

__device__ __forceinline__ unsigned short f2bf(float f) {
  unsigned u = __float_as_uint(f);
  u += 0x7fffu + ((u >> 16) & 1u);
  return (unsigned short)(u >> 16);
}
// pack two f32 -> two bf16 (truncation) in one v_perm_b32
__device__ __forceinline__ unsigned packbf(float a, float b) {
  return __builtin_amdgcn_perm(__float_as_uint(b), __float_as_uint(a), 0x07060302u);
}

// ---------------- pooled = mean over spatial ----------------
__global__ __launch_bounds__(256) void pool_kernel(const float* __restrict__ x,
                                                   float* __restrict__ pooled) {
  int bc = blockIdx.x;  // b*64 + c
  const float* p = x + (size_t)bc * N_TOK;
  float s = 0.f;
  for (int t = threadIdx.x; t < N_TOK; t += 256) s += p[t];
#pragma unroll
  for (int off = 32; off >= 1; off >>= 1) s += __shfl_down(s, off, 64);
  __shared__ float red[4];
  int wid = threadIdx.x >> 6, lane = threadIdx.x & 63;
  if (lane == 0) red[wid] = s;
  __syncthreads();
  if (threadIdx.x == 0)
    pooled[bc] = (red[0] + red[1] + red[2] + red[3]) * (1.0f / N_TOK);
}

// ---------------- gate = sigmoid(cg2(relu(cg1(pooled)))) ----------------
__global__ __launch_bounds__(128) void gate_kernel(
    const float* __restrict__ pooled, const float* __restrict__ cg1_w,
    const float* __restrict__ cg1_b, const float* __restrict__ cg2_w,
    const float* __restrict__ cg2_b, float* __restrict__ gate) {
  __shared__ float hl[B_SZ][BOT];
  int tid = threadIdx.x;
  if (tid < B_SZ * BOT) {
    int b = tid >> 4, i = tid & 15;
    float a = cg1_b[i];
    for (int c = 0; c < C_DIM; ++c)
      a += cg1_w[i * C_DIM + c] * pooled[b * C_DIM + c];
    hl[b][i] = a > 0.f ? a : 0.f;
  }
  __syncthreads();
  {
    int b = tid >> 6, c = tid & 63;
    float z = cg2_b[c];
    for (int j = 0; j < BOT; ++j) z += cg2_w[c * BOT + j] * hl[b][j];
    gate[b * C_DIM + c] = 1.f / (1.f + __expf(-z));
  }
}

// ---------------- projections via MFMA (16x16x32, verified layout) ----------------
// wave-task = (mat, b, 16-token tile). mat0=theta (pre-scaled log2e/T), mat1=phi, mat2=g.
// Q/K: [B][N][32] bf16 row-major. VT: [B][32][N] bf16.
__global__ __launch_bounds__(256) void proj_kernel(
    const float* __restrict__ x, const float* __restrict__ g_w,
    const float* __restrict__ theta_w, const float* __restrict__ phi_w,
    unsigned short* __restrict__ Q, unsigned short* __restrict__ K,
    unsigned short* __restrict__ VT) {
  const int lane = threadIdx.x & 63;
  const int m = lane & 15, quad = lane >> 4;
  int task = blockIdx.x * 4 + (threadIdx.x >> 6);  // 0..3455
  int mat = task / 1152;
  int r0 = task % 1152;
  int b = r0 / 576;
  int n0 = (r0 % 576) * 16;
  const float* wsrc = (mat == 0) ? theta_w : ((mat == 1) ? phi_w : g_w);
  // fold 1/TEMPERATURE and log2(e) into theta so softmax is bare exp2
  const float scale = (mat == 0) ? 0.96179669439f : 1.0f;  // log2(e)/1.5

  bf16x8 afr[2][2];  // [itile][cstep] of W
#pragma unroll
  for (int it = 0; it < 2; ++it)
#pragma unroll
    for (int cs = 0; cs < 2; ++cs) {
      const float* wp = wsrc + (it * 16 + m) * C_DIM + cs * 32 + quad * 8;
      union { unsigned u[4]; bf16x8 v; } t;
#pragma unroll
      for (int j = 0; j < 4; ++j)
        t.u[j] = (unsigned)f2bf(wp[2 * j] * scale) |
                 ((unsigned)f2bf(wp[2 * j + 1] * scale) << 16);
      afr[it][cs] = t.v;
    }

  const float* xb = x + (size_t)b * C_DIM * N_TOK + n0 + m;
  bf16x8 bfr[2];
#pragma unroll
  for (int cs = 0; cs < 2; ++cs) {
    union { unsigned u[4]; bf16x8 v; } t;
#pragma unroll
    for (int j = 0; j < 4; ++j) {
      float v0 = xb[(size_t)(cs * 32 + quad * 8 + 2 * j) * N_TOK];
      float v1 = xb[(size_t)(cs * 32 + quad * 8 + 2 * j + 1) * N_TOK];
      t.u[j] = (unsigned)f2bf(v0) | ((unsigned)f2bf(v1) << 16);
    }
    bfr[cs] = t.v;
  }

  f32x4 acc[2] = {{0.f, 0.f, 0.f, 0.f}, {0.f, 0.f, 0.f, 0.f}};
#pragma unroll
  for (int cs = 0; cs < 2; ++cs)
#pragma unroll
    for (int it = 0; it < 2; ++it)
      acc[it] = __builtin_amdgcn_mfma_f32_16x16x32_bf16(afr[it][cs], bfr[cs],
                                                        acc[it], 0, 0, 0);
  // C layout: col(n)=lane&15, row(i)=quad*4+r
  if (mat < 2) {
    unsigned short* dst =
        ((mat == 0) ? Q : K) + ((size_t)b * N_TOK + n0 + m) * I_DIM;
#pragma unroll
    for (int it = 0; it < 2; ++it) {
      unsigned u0 = (unsigned)f2bf(acc[it][0]) | ((unsigned)f2bf(acc[it][1]) << 16);
      unsigned u1 = (unsigned)f2bf(acc[it][2]) | ((unsigned)f2bf(acc[it][3]) << 16);
      *(uint2*)(dst + it * 16 + quad * 4) = make_uint2(u0, u1);
    }
  } else {
#pragma unroll
    for (int it = 0; it < 2; ++it)
#pragma unroll
      for (int r = 0; r < 4; ++r)
        VT[((size_t)b * I_DIM + it * 16 + quad * 4 + r) * N_TOK + n0 + m] =
            f2bf(acc[it][r]);
  }
}

// ---------------- flash attention, S^T form, no LDS, no barriers ----------------
// S^T = K@Q^T via 32x32x16; P^T C-regs hold consecutive kv per lane -> A-operand
// of Y=P@V rebuilt with xor-32 lane swaps. Softmax has no max (logits tiny);
// exp2 with scale folded into Q. Rowsum on VALU.
__global__ __launch_bounds__(256, 4) void attn_kernel(
    const unsigned short* __restrict__ Q, const unsigned short* __restrict__ Kg,
    const unsigned short* __restrict__ VT, float* __restrict__ Ypart,
    float* __restrict__ Lpart, int tps) {
  const int lane = threadIdx.x & 63;
  const int l32 = lane & 31, h = lane >> 5;
  const int qw = blockIdx.x * 4 + (threadIdx.x >> 6);
  const int ks = blockIdx.y, b = blockIdx.z;
  const int q0 = qw * 32;
  const unsigned short* Qb = Q + (size_t)b * N_TOK * I_DIM;
  const unsigned short* Kb = Kg + (size_t)b * N_TOK * I_DIM;
  const unsigned short* Vb = VT + (size_t)b * I_DIM * N_TOK;

  // Q as B-operand (B[k=c][n=q]): same memory layout as A-fragments
  bf16x8 bq0 = *(const bf16x8*)(Qb + (size_t)(q0 + l32) * I_DIM + h * 8);
  bf16x8 bq1 = *(const bf16x8*)(Qb + (size_t)(q0 + l32) * I_DIM + 16 + h * 8);

  const f32x16 zz = {};
  f32x16 accy = {};
  float lsum = 0.f;

  const int kt0 = ks * tps;
  for (int kt = kt0; kt < kt0 + tps; ++kt) {
    const int k0 = kt * 64;
    const unsigned short* kp = Kb + (size_t)(k0 + l32) * I_DIM + h * 8;
    bf16x8 ak00 = *(const bf16x8*)(kp);
    bf16x8 ak01 = *(const bf16x8*)(kp + 16);
    bf16x8 ak10 = *(const bf16x8*)(kp + 32 * I_DIM);
    bf16x8 ak11 = *(const bf16x8*)(kp + 32 * I_DIM + 16);
    const unsigned short* vp = Vb + (size_t)l32 * N_TOK + k0 + h * 8;
    bf16x8 bv[4];
    bv[0] = *(const bf16x8*)(vp);
    bv[1] = *(const bf16x8*)(vp + 16);
    bv[2] = *(const bf16x8*)(vp + 32);
    bv[3] = *(const bf16x8*)(vp + 48);

    // S^T tiles: D[kv][q], col(q)=lane&31, row(kv)=(reg&3)+8*(reg>>2)+4*h
    f32x16 s0 = __builtin_amdgcn_mfma_f32_32x32x16_bf16(ak00, bq0, zz, 0, 0, 0);
    s0 = __builtin_amdgcn_mfma_f32_32x32x16_bf16(ak01, bq1, s0, 0, 0, 0);
    f32x16 s1 = __builtin_amdgcn_mfma_f32_32x32x16_bf16(ak10, bq0, zz, 0, 0, 0);
    s1 = __builtin_amdgcn_mfma_f32_32x32x16_bf16(ak11, bq1, s1, 0, 0, 0);

    // P = exp2(S) (scale pre-folded); rowsum on VALU; pack pairs with v_perm
    unsigned pk[2][8];
    {
      float e[16];
#pragma unroll
      for (int r = 0; r < 16; ++r) { e[r] = exp2f(s0[r]); lsum += e[r]; }
#pragma unroll
      for (int i = 0; i < 8; ++i) pk[0][i] = packbf(e[2 * i], e[2 * i + 1]);
#pragma unroll
      for (int r = 0; r < 16; ++r) { e[r] = exp2f(s1[r]); lsum += e[r]; }
#pragma unroll
      for (int i = 0; i < 8; ++i) pk[1][i] = packbf(e[2 * i], e[2 * i + 1]);
    }

    // Y += P@V: rebuild P A-fragments via xor-32 swaps
#pragma unroll
    for (int s = 0; s < 4; ++s) {
      const int t = s >> 1, E2 = 4 * (s & 1);
      unsigned a0 = pk[t][E2 + 0], a1 = pk[t][E2 + 1];
      unsigned b0 = pk[t][E2 + 2], b1 = pk[t][E2 + 3];
      unsigned xa0 = __shfl_xor(a0, 32, 64), xa1 = __shfl_xor(a1, 32, 64);
      unsigned xb0 = __shfl_xor(b0, 32, 64), xb1 = __shfl_xor(b1, 32, 64);
      union { unsigned u[4]; bf16x8 v; } fu;
      fu.u[0] = h ? xb0 : a0;
      fu.u[1] = h ? xb1 : a1;
      fu.u[2] = h ? b0 : xa0;
      fu.u[3] = h ? b1 : xa1;
      accy = __builtin_amdgcn_mfma_f32_32x32x16_bf16(fu.v, bv[s], accy, 0, 0, 0);
    }
  }

  lsum += __shfl_xor(lsum, 32, 64);

  const size_t base = (size_t)(ks * B_SZ + b) * N_TOK + q0;
#pragma unroll
  for (int R = 0; R < 4; ++R)
#pragma unroll
    for (int r = 0; r < 4; ++r)
      Ypart[(base + r + 8 * R + 4 * h) * I_DIM + l32] = accy[4 * R + r];
  if (h == 0) Lpart[base + l32] = lsum;
}

// ---------------- epilogue: reduce partials -> LDS, then GEMV + residual ----------------
__global__ __launch_bounds__(256) void epilogue_kernel(
    const float* __restrict__ x, const float* __restrict__ W_w,
    const float* __restrict__ gate, const float* __restrict__ Ypart,
    const float* __restrict__ Lpart, float* __restrict__ out, int KS) {
  __shared__ float Ysh[64][33];
  __shared__ float lsh[64];
  __shared__ float gsh[64];
  const int t = threadIdx.x;
  const int b = blockIdx.y;
  const int n0 = blockIdx.x * 64;

  {  // phase 1: reduce Ypart over KS into LDS
    int nl = t >> 2, i0 = (t & 3) * 8;
    float4 s0 = make_float4(0.f, 0.f, 0.f, 0.f), s1 = s0;
    for (int ks = 0; ks < KS; ++ks) {
      const float* yp =
          Ypart + ((size_t)(ks * B_SZ + b) * N_TOK + n0 + nl) * I_DIM + i0;
      float4 v0 = *(const float4*)(yp);
      float4 v1 = *(const float4*)(yp + 4);
      s0.x += v0.x; s0.y += v0.y; s0.z += v0.z; s0.w += v0.w;
      s1.x += v1.x; s1.y += v1.y; s1.z += v1.z; s1.w += v1.w;
    }
    Ysh[nl][i0 + 0] = s0.x; Ysh[nl][i0 + 1] = s0.y;
    Ysh[nl][i0 + 2] = s0.z; Ysh[nl][i0 + 3] = s0.w;
    Ysh[nl][i0 + 4] = s1.x; Ysh[nl][i0 + 5] = s1.y;
    Ysh[nl][i0 + 6] = s1.z; Ysh[nl][i0 + 7] = s1.w;
    if (t < 64) {
      float ls = 0.f;
      for (int ks = 0; ks < KS; ++ks)
        ls += Lpart[(size_t)(ks * B_SZ + b) * N_TOK + n0 + t];
      lsh[t] = ls;
      gsh[t] = gate[b * C_DIM + t];
    }
  }
  __syncthreads();

  // phase 2: out = x + 0.8*gate*(W_w @ y)/l ; c-range per wave (W reads scalar)
  const int n = t & 63, cg = t >> 6;
  float y[I_DIM];
#pragma unroll
  for (int i = 0; i < I_DIM; ++i) y[i] = Ysh[n][i];
  const float inv = 1.0f / lsh[n];
  const float* xb = x + ((size_t)b * C_DIM + cg * 16) * N_TOK + n0 + n;
  float* ob = out + ((size_t)b * C_DIM + cg * 16) * N_TOK + n0 + n;
#pragma unroll
  for (int c16 = 0; c16 < 16; ++c16) {
    const int c = cg * 16 + c16;
    float sacc = 0.f;
#pragma unroll
    for (int i = 0; i < I_DIM; ++i) sacc += W_w[c * I_DIM + i] * y[i];
    ob[(size_t)c16 * N_TOK] =
        xb[(size_t)c16 * N_TOK] + 0.8f * gsh[c] * inv * sacc;
  }
}

extern "C" void kernel_launch(void* const* d_in, const int* in_sizes, int n_in,
                              void* d_out, int out_size, void* d_ws, size_t ws_size,
                              hipStream_t stream) {
  const float* x = (const float*)d_in[0];
  const float* g_w = (const float*)d_in[1];
  const float* theta_w = (const float*)d_in[2];
  const float* phi_w = (const float*)d_in[3];
  const float* W_w = (const float*)d_in[4];
  const float* cg1_w = (const float*)d_in[5];
  const float* cg1_b = (const float*)d_in[6];
  const float* cg2_w = (const float*)d_in[7];
  const float* cg2_b = (const float*)d_in[8];
  float* out = (float*)d_out;

  char* w = (char*)d_ws;
  const size_t bfsz = (size_t)B_SZ * N_TOK * I_DIM * sizeof(unsigned short);
  unsigned short* Qb = (unsigned short*)(w);
  unsigned short* Kb = (unsigned short*)(w + bfsz);
  unsigned short* VT = (unsigned short*)(w + 2 * bfsz);
  float* pooled = (float*)(w + 3 * bfsz);
  float* gate = pooled + B_SZ * C_DIM;
  char* w2 = w + 3 * bfsz + 1024;

  int KS = 8;
  {
    const size_t per = (size_t)B_SZ * N_TOK * sizeof(float) * (I_DIM + 1);
    while (KS > 1 && (3 * bfsz + 1024 + (size_t)KS * per) > ws_size) KS >>= 1;
  }
  float* Lpart = (float*)w2;
  float* Ypart = (float*)(w2 + (size_t)KS * B_SZ * N_TOK * sizeof(float));
  int tps = N_TILES / KS;

  proj_kernel<<<dim3(864), 256, 0, stream>>>(x, g_w, theta_w, phi_w, Qb, Kb, VT);
  pool_kernel<<<dim3(B_SZ * C_DIM), 256, 0, stream>>>(x, pooled);
  gate_kernel<<<dim3(1), 128, 0, stream>>>(pooled, cg1_w, cg1_b, cg2_w, cg2_b, gate);
  attn_kernel<<<dim3(72, KS, B_SZ), 256, 0, stream>>>(Qb, Kb, VT, Ypart, Lpart, tps);
  epilogue_kernel<<<dim3(N_TOK / 64, B_SZ), 256, 0, stream>>>(x, W_w, gate,
                                                              Ypart, Lpart, out, KS);
}

// Round 3
// 173.640 us; speedup vs baseline: 1.0882x; 1.0882x over previous
//
#include <hip/hip_runtime.h>

#define N_TOK 9216
#define C_DIM 64
#define I_DIM 32
#define BOT 16
#define B_SZ 2
#define N_TILES 144  // N_TOK / 64

typedef short bf16x8 __attribute__((ext_vector_type(8)));
typedef float f32x4 __attribute__((ext_vector_type(4)));
typedef float f32x16 __attribute__((ext_vector_type(16)));

// pack two f32 -> two bf16 (truncation) in one v_perm_b32
__device__ __forceinline__ unsigned packbf(float a, float b) {
  return __builtin_amdgcn_perm(__float_as_uint(b), __float_as_uint(a), 0x07060302u);
}
__device__ __forceinline__ unsigned short bftrunc(float f) {
  return (unsigned short)(__float_as_uint(f) >> 16);
}

// ---------------- pooled = mean over spatial ----------------
__global__ __launch_bounds__(256) void pool_kernel(const float* __restrict__ x,
                                                   float* __restrict__ pooled) {
  int bc = blockIdx.x;  // b*64 + c
  const float* p = x + (size_t)bc * N_TOK;
  float s = 0.f;
  for (int t = threadIdx.x; t < N_TOK; t += 256) s += p[t];
#pragma unroll
  for (int off = 32; off >= 1; off >>= 1) s += __shfl_down(s, off, 64);
  __shared__ float red[4];
  int wid = threadIdx.x >> 6, lane = threadIdx.x & 63;
  if (lane == 0) red[wid] = s;
  __syncthreads();
  if (threadIdx.x == 0)
    pooled[bc] = (red[0] + red[1] + red[2] + red[3]) * (1.0f / N_TOK);
}

// ---------------- projections via MFMA (16x16x32) ----------------
// wave-task = (mat, b, 16-token tile). mat0=theta (pre-scaled log2e/T), mat1=phi, mat2=g.
// Q/K: [B][N][32] bf16 row-major. VT: [B][32][N] bf16.
__global__ __launch_bounds__(256) void proj_kernel(
    const float* __restrict__ x, const float* __restrict__ g_w,
    const float* __restrict__ theta_w, const float* __restrict__ phi_w,
    unsigned short* __restrict__ Q, unsigned short* __restrict__ K,
    unsigned short* __restrict__ VT) {
  const int lane = threadIdx.x & 63;
  const int m = lane & 15, quad = lane >> 4;
  int task = blockIdx.x * 4 + (threadIdx.x >> 6);  // 0..3455
  int mat = task / 1152;
  int r0 = task % 1152;
  int b = r0 / 576;
  int n0 = (r0 % 576) * 16;
  const float* wsrc = (mat == 0) ? theta_w : ((mat == 1) ? phi_w : g_w);
  const float scale = (mat == 0) ? 0.96179669439f : 1.0f;  // log2(e)/1.5

  bf16x8 afr[2][2];  // [itile][cstep] of W
#pragma unroll
  for (int it = 0; it < 2; ++it)
#pragma unroll
    for (int cs = 0; cs < 2; ++cs) {
      const float* wp = wsrc + (it * 16 + m) * C_DIM + cs * 32 + quad * 8;
      union { unsigned u[4]; bf16x8 v; } t;
#pragma unroll
      for (int j = 0; j < 4; ++j)
        t.u[j] = packbf(wp[2 * j] * scale, wp[2 * j + 1] * scale);
      afr[it][cs] = t.v;
    }

  const float* xb = x + (size_t)b * C_DIM * N_TOK + n0 + m;
  bf16x8 bfr[2];
#pragma unroll
  for (int cs = 0; cs < 2; ++cs) {
    union { unsigned u[4]; bf16x8 v; } t;
#pragma unroll
    for (int j = 0; j < 4; ++j) {
      float v0 = xb[(size_t)(cs * 32 + quad * 8 + 2 * j) * N_TOK];
      float v1 = xb[(size_t)(cs * 32 + quad * 8 + 2 * j + 1) * N_TOK];
      t.u[j] = packbf(v0, v1);
    }
    bfr[cs] = t.v;
  }

  f32x4 acc[2] = {{0.f, 0.f, 0.f, 0.f}, {0.f, 0.f, 0.f, 0.f}};
#pragma unroll
  for (int cs = 0; cs < 2; ++cs)
#pragma unroll
    for (int it = 0; it < 2; ++it)
      acc[it] = __builtin_amdgcn_mfma_f32_16x16x32_bf16(afr[it][cs], bfr[cs],
                                                        acc[it], 0, 0, 0);
  // C layout: col(n)=lane&15, row(i)=quad*4+r
  if (mat < 2) {
    unsigned short* dst =
        ((mat == 0) ? Q : K) + ((size_t)b * N_TOK + n0 + m) * I_DIM;
#pragma unroll
    for (int it = 0; it < 2; ++it) {
      unsigned u0 = packbf(acc[it][0], acc[it][1]);
      unsigned u1 = packbf(acc[it][2], acc[it][3]);
      *(uint2*)(dst + it * 16 + quad * 4) = make_uint2(u0, u1);
    }
  } else {
#pragma unroll
    for (int it = 0; it < 2; ++it)
#pragma unroll
      for (int r = 0; r < 4; ++r)
        VT[((size_t)b * I_DIM + it * 16 + quad * 4 + r) * N_TOK + n0 + m] =
            bftrunc(acc[it][r]);
  }
}

// ---------------- flash attention, S^T form, per-wave LDS transpose, no barriers ----------------
// S^T = K@Q^T via 32x32x16 (D: col q=lane&31, row kv=(reg&3)+8*(reg>>2)+4*(lane>>5)).
// P^T packed to bf16, written as ds_write_b64 into per-wave Pw[q][kv] (stride 68),
// read back as A-fragments (ds_read_b64 pairs). No shuffles, no __syncthreads.
__global__ __launch_bounds__(256, 4) void attn_kernel(
    const unsigned short* __restrict__ Q, const unsigned short* __restrict__ Kg,
    const unsigned short* __restrict__ VT, float* __restrict__ Ypart,
    float* __restrict__ Lpart, int tps) {
  const int lane = threadIdx.x & 63;
  const int l32 = lane & 31, h = lane >> 5;
  const int wid = threadIdx.x >> 6;
  const int qw = blockIdx.x * 4 + wid;
  const int ks = blockIdx.y, b = blockIdx.z;
  const int q0 = qw * 32;
  const unsigned short* Qb = Q + (size_t)b * N_TOK * I_DIM;
  const unsigned short* Kb = Kg + (size_t)b * N_TOK * I_DIM;
  const unsigned short* Vb = VT + (size_t)b * I_DIM * N_TOK;

  __shared__ __align__(16) unsigned short Pw[4][32][68];
  unsigned short(*P)[68] = Pw[wid];

  // Q as B-operand: B[k=c][n=q], lane holds q=l32, c=8h+j
  bf16x8 bq0 = *(const bf16x8*)(Qb + (size_t)(q0 + l32) * I_DIM + h * 8);
  bf16x8 bq1 = *(const bf16x8*)(Qb + (size_t)(q0 + l32) * I_DIM + 16 + h * 8);

  const f32x16 zz = {};
  f32x16 accy = {};
  float lsum = 0.f;

  const int kt0 = ks * tps;
  for (int kt = kt0; kt < kt0 + tps; ++kt) {
    const int k0 = kt * 64;
    const unsigned short* kp = Kb + (size_t)(k0 + l32) * I_DIM + h * 8;
    bf16x8 ak00 = *(const bf16x8*)(kp);
    bf16x8 ak01 = *(const bf16x8*)(kp + 16);
    bf16x8 ak10 = *(const bf16x8*)(kp + 32 * I_DIM);
    bf16x8 ak11 = *(const bf16x8*)(kp + 32 * I_DIM + 16);
    const unsigned short* vp = Vb + (size_t)l32 * N_TOK + k0 + h * 8;
    bf16x8 bv[4];
    bv[0] = *(const bf16x8*)(vp);
    bv[1] = *(const bf16x8*)(vp + 16);
    bv[2] = *(const bf16x8*)(vp + 32);
    bv[3] = *(const bf16x8*)(vp + 48);

    // S^T tiles (kv 0-31 and 32-63)
    f32x16 s0 = __builtin_amdgcn_mfma_f32_32x32x16_bf16(ak00, bq0, zz, 0, 0, 0);
    s0 = __builtin_amdgcn_mfma_f32_32x32x16_bf16(ak01, bq1, s0, 0, 0, 0);
    f32x16 s1 = __builtin_amdgcn_mfma_f32_32x32x16_bf16(ak10, bq0, zz, 0, 0, 0);
    s1 = __builtin_amdgcn_mfma_f32_32x32x16_bf16(ak11, bq1, s1, 0, 0, 0);

    // P = exp2(S) (scale folded into Q); pack; write per-wave LDS rows
#pragma unroll
    for (int t = 0; t < 2; ++t) {
      const f32x16 sv = t ? s1 : s0;
      float e[16];
#pragma unroll
      for (int r = 0; r < 16; ++r) {
        e[r] = __builtin_amdgcn_exp2f(sv[r]);
        lsum += e[r];
      }
      unsigned pk[8];
#pragma unroll
      for (int i = 0; i < 8; ++i) pk[i] = packbf(e[2 * i], e[2 * i + 1]);
      // reg pairs (2i,2i+1) are kv {0,1,2,3},{8..11},{16..19},{24..27} (+4h, +32t)
      unsigned short* row = &P[l32][t * 32 + 4 * h];
      *(uint2*)(row) = make_uint2(pk[0], pk[1]);
      *(uint2*)(row + 8) = make_uint2(pk[2], pk[3]);
      *(uint2*)(row + 16) = make_uint2(pk[4], pk[5]);
      *(uint2*)(row + 24) = make_uint2(pk[6], pk[7]);
    }

    // Y += P@V: A-fragment = P[q=l32][kv=16s+8h..+7]
#pragma unroll
    for (int s = 0; s < 4; ++s) {
      union { uint2 d[2]; bf16x8 v; } ap;
      const unsigned short* rp = &P[l32][16 * s + 8 * h];
      ap.d[0] = *(const uint2*)(rp);
      ap.d[1] = *(const uint2*)(rp + 4);
      accy = __builtin_amdgcn_mfma_f32_32x32x16_bf16(ap.v, bv[s], accy, 0, 0, 0);
    }
  }

  lsum += __shfl_xor(lsum, 32, 64);

  const size_t base = (size_t)(ks * B_SZ + b) * N_TOK + q0;
#pragma unroll
  for (int R = 0; R < 4; ++R)
#pragma unroll
    for (int r = 0; r < 4; ++r)
      Ypart[(base + r + 8 * R + 4 * h) * I_DIM + l32] = accy[4 * R + r];
  if (h == 0) Lpart[base + l32] = lsum;
}

// ---------------- epilogue: gate + reduce partials + GEMV + residual ----------------
__global__ __launch_bounds__(256) void epilogue_kernel(
    const float* __restrict__ x, const float* __restrict__ W_w,
    const float* __restrict__ pooled, const float* __restrict__ cg1_w,
    const float* __restrict__ cg1_b, const float* __restrict__ cg2_w,
    const float* __restrict__ cg2_b, const float* __restrict__ Ypart,
    const float* __restrict__ Lpart, float* __restrict__ out, int KS) {
  __shared__ float Ysh[64][33];
  __shared__ float lsh[64];
  __shared__ float gsh[64];
  __shared__ float hl[BOT];
  const int t = threadIdx.x;
  const int b = blockIdx.y;
  const int n0 = blockIdx.x * 64;

  // gate stage 1: hl = relu(cg1 @ pooled + cg1_b)
  if (t < BOT) {
    float a = cg1_b[t];
#pragma unroll
    for (int c = 0; c < C_DIM; ++c)
      a += cg1_w[t * C_DIM + c] * pooled[b * C_DIM + c];
    hl[t] = a > 0.f ? a : 0.f;
  }

  {  // phase 1: reduce Ypart over KS into LDS
    int nl = t >> 2, i0 = (t & 3) * 8;
    float4 s0 = make_float4(0.f, 0.f, 0.f, 0.f), s1 = s0;
    for (int ks = 0; ks < KS; ++ks) {
      const float* yp =
          Ypart + ((size_t)(ks * B_SZ + b) * N_TOK + n0 + nl) * I_DIM + i0;
      float4 v0 = *(const float4*)(yp);
      float4 v1 = *(const float4*)(yp + 4);
      s0.x += v0.x; s0.y += v0.y; s0.z += v0.z; s0.w += v0.w;
      s1.x += v1.x; s1.y += v1.y; s1.z += v1.z; s1.w += v1.w;
    }
    Ysh[nl][i0 + 0] = s0.x; Ysh[nl][i0 + 1] = s0.y;
    Ysh[nl][i0 + 2] = s0.z; Ysh[nl][i0 + 3] = s0.w;
    Ysh[nl][i0 + 4] = s1.x; Ysh[nl][i0 + 5] = s1.y;
    Ysh[nl][i0 + 6] = s1.z; Ysh[nl][i0 + 7] = s1.w;
    if (t < 64) {
      float ls = 0.f;
      for (int ks = 0; ks < KS; ++ks)
        ls += Lpart[(size_t)(ks * B_SZ + b) * N_TOK + n0 + t];
      lsh[t] = ls;
    }
  }
  __syncthreads();

  // gate stage 2 (folds 0.8): gsh = 0.8*sigmoid(cg2 @ hl + cg2_b)
  if (t < C_DIM) {
    float z = cg2_b[t];
#pragma unroll
    for (int j = 0; j < BOT; ++j) z += cg2_w[t * BOT + j] * hl[j];
    gsh[t] = 0.8f / (1.f + __expf(-z));
  }
  __syncthreads();

  // phase 2: out = x + gsh*(W_w @ y)/l ; c-range per wave (W reads scalar)
  const int n = t & 63, cg = t >> 6;
  float y[I_DIM];
#pragma unroll
  for (int i = 0; i < I_DIM; ++i) y[i] = Ysh[n][i];
  const float inv = 1.0f / lsh[n];
  const float* xb = x + ((size_t)b * C_DIM + cg * 16) * N_TOK + n0 + n;
  float* ob = out + ((size_t)b * C_DIM + cg * 16) * N_TOK + n0 + n;
#pragma unroll
  for (int c16 = 0; c16 < 16; ++c16) {
    const int c = cg * 16 + c16;
    float sacc = 0.f;
#pragma unroll
    for (int i = 0; i < I_DIM; ++i) sacc += W_w[c * I_DIM + i] * y[i];
    ob[(size_t)c16 * N_TOK] = xb[(size_t)c16 * N_TOK] + gsh[c] * inv * sacc;
  }
}

extern "C" void kernel_launch(void* const* d_in, const int* in_sizes, int n_in,
                              void* d_out, int out_size, void* d_ws, size_t ws_size,
                              hipStream_t stream) {
  const float* x = (const float*)d_in[0];
  const float* g_w = (const float*)d_in[1];
  const float* theta_w = (const float*)d_in[2];
  const float* phi_w = (const float*)d_in[3];
  const float* W_w = (const float*)d_in[4];
  const float* cg1_w = (const float*)d_in[5];
  const float* cg1_b = (const float*)d_in[6];
  const float* cg2_w = (const float*)d_in[7];
  const float* cg2_b = (const float*)d_in[8];
  float* out = (float*)d_out;

  char* w = (char*)d_ws;
  const size_t bfsz = (size_t)B_SZ * N_TOK * I_DIM * sizeof(unsigned short);
  unsigned short* Qb = (unsigned short*)(w);
  unsigned short* Kb = (unsigned short*)(w + bfsz);
  unsigned short* VT = (unsigned short*)(w + 2 * bfsz);
  float* pooled = (float*)(w + 3 * bfsz);
  char* w2 = w + 3 * bfsz + 1024;

  int KS = 8;
  {
    const size_t per = (size_t)B_SZ * N_TOK * sizeof(float) * (I_DIM + 1);
    while (KS > 1 && (3 * bfsz + 1024 + (size_t)KS * per) > ws_size) KS >>= 1;
  }
  float* Lpart = (float*)w2;
  float* Ypart = (float*)(w2 + (size_t)KS * B_SZ * N_TOK * sizeof(float));
  int tps = N_TILES / KS;

  proj_kernel<<<dim3(864), 256, 0, stream>>>(x, g_w, theta_w, phi_w, Qb, Kb, VT);
  pool_kernel<<<dim3(B_SZ * C_DIM), 256, 0, stream>>>(x, pooled);
  attn_kernel<<<dim3(72, KS, B_SZ), 256, 0, stream>>>(Qb, Kb, VT, Ypart, Lpart, tps);
  epilogue_kernel<<<dim3(N_TOK / 64, B_SZ), 256, 0, stream>>>(
      x, W_w, pooled, cg1_w, cg1_b, cg2_w, cg2_b, Ypart, Lpart, out, KS);
}